// Round 1
// baseline (490.218 us; speedup 1.0000x reference)
//
#include <hip/hip_runtime.h>
#include <hip/hip_bf16.h>

#define NB 512
#define NL 1024
#define NT 48

__device__ __forceinline__ float rfl(float x) {
    return __int_as_float(__builtin_amdgcn_readfirstlane(__float_as_int(x)));
}

__global__ void __launch_bounds__(64) crf_nll_kernel(
    const float* __restrict__ feats,
    const float* __restrict__ trans,
    const int* __restrict__ tags,
    const int* __restrict__ mask,
    float* __restrict__ out)
{
    const int b = blockIdx.x;
    const int lane = threadIdx.x;
    const int jl = lane < NT ? lane : NT - 1;   // clamp for lanes 48..63 (avoid OOB)

    __shared__ __align__(16) float eBuf[64];

    // ET column j in registers: et[i] = exp(trans[i][j])
    float et[NT];
    #pragma unroll
    for (int i = 0; i < NT; ++i) et[i] = __expf(trans[i * NT + jl]);

    const float* fb = feats + (size_t)b * NL * NT;
    const int* tgp = tags + b * NL;
    const int* mkp = mask + b * NL;

    float r = -400.f;      // alpha = base + r (r relative to lane0)
    float base = 0.f;
    float goldT = 0.f;     // uniform accumulator (trans scores)
    float goldE = 0.f;     // per-lane accumulator (emit scores)
    int tgprev = 0;

    float emA[8], emB[8];
    int   tgA[8], tgB[8], mvA[8], mvB[8];

    // prefetch chunk 0
    #pragma unroll
    for (int k = 0; k < 8; ++k) {
        emA[k] = fb[k * NT + jl];
        tgA[k] = tgp[k];
        mvA[k] = mkp[k];
    }

    auto run_chunk = [&](int c,
                         float (&cur)[8], int (&ctg)[8], int (&cmv)[8],
                         float (&nxt)[8], int (&ntg)[8], int (&nmv)[8]) {
        const int cn = c + 1;
        if (cn < NL / 8) {   // prefetch next chunk
            #pragma unroll
            for (int k = 0; k < 8; ++k) {
                int l = cn * 8 + k;
                nxt[k] = fb[l * NT + jl];
                ntg[k] = tgp[l];
                nmv[k] = mkp[l];
            }
        }
        #pragma unroll
        for (int k = 0; k < 8; ++k) {
            const int l = c * 8 + k;
            const float emit = cur[k];
            const int tg = ctg[k];
            const int mv = cmv[k];
            if (l == 0) {
                // alpha0 = f[0]
                float t0 = rfl(emit);
                base = t0;
                r = (lane < NT) ? emit - t0 : -400.f;
                if (mv > 0 && lane == tg) goldE += emit;
            } else if (mv > 0) {
                float e = __expf(r);
                eBuf[lane] = e;
                __syncthreads();   // single-wave block: cheap; guarantees LDS visibility
                const float4* e4 = reinterpret_cast<const float4*>(eBuf);
                float a0 = 0.f, a1 = 0.f, a2 = 0.f, a3 = 0.f;
                #pragma unroll
                for (int q = 0; q < 12; ++q) {
                    float4 ev = e4[q];             // broadcast read, all lanes same addr
                    a0 = fmaf(ev.x, et[4*q+0], a0);
                    a1 = fmaf(ev.y, et[4*q+1], a1);
                    a2 = fmaf(ev.z, et[4*q+2], a2);
                    a3 = fmaf(ev.w, et[4*q+3], a3);
                }
                float s = (a0 + a1) + (a2 + a3);
                float t = __logf(s) + emit;        // new alpha (relative to base)
                float t0 = rfl(t);
                base += t0;
                r = (lane < NT) ? t - t0 : -400.f;
                goldT += trans[tgprev * NT + tg];  // uniform scalar load + uniform add
                if (lane == tg) goldE += emit;
            }
            tgprev = tg;
        }
    };

    for (int c = 0; c < NL / 8; c += 2) {
        run_chunk(c,     emA, tgA, mvA, emB, tgB, mvB);
        run_chunk(c + 1, emB, tgB, mvB, emA, tgA, mvA);
    }

    // logZ = base + logsumexp over lanes of r
    float v = (lane < NT) ? r : -1e30f;
    float mx = v;
    #pragma unroll
    for (int o = 32; o > 0; o >>= 1) mx = fmaxf(mx, __shfl_xor(mx, o, 64));
    float se = __expf(v - mx);
    float ss = se;
    #pragma unroll
    for (int o = 32; o > 0; o >>= 1) ss += __shfl_xor(ss, o, 64);
    float ge = goldE;
    #pragma unroll
    for (int o = 32; o > 0; o >>= 1) ge += __shfl_xor(ge, o, 64);

    float logZ = base + mx + __logf(ss);
    float nll = logZ - (goldT + ge);
    if (lane == 0) out[b] = nll;
}

extern "C" void kernel_launch(void* const* d_in, const int* in_sizes, int n_in,
                              void* d_out, int out_size, void* d_ws, size_t ws_size,
                              hipStream_t stream) {
    const float* feats = (const float*)d_in[0];
    const float* trans = (const float*)d_in[1];
    const int*   tags  = (const int*)d_in[2];
    const int*   mask  = (const int*)d_in[3];
    float* out = (float*)d_out;

    crf_nll_kernel<<<dim3(NB), dim3(64), 0, stream>>>(feats, trans, tags, mask, out);
}